// Round 3
// baseline (176.529 us; speedup 1.0000x reference)
//
#include <hip/hip_runtime.h>

#define L_LEN  1024
#define FDIM   16
#define PERIOD 24
#define HDIM   128
#define BATCH  1024
#define DDIM   (L_LEN*FDIM)      // 16384
#define NH3    (3*HDIM)          // 384
#define THALF  12
#define NCLS   10
#define FH     (FDIM*HDIM)       // 2048
#define NLB    16

typedef short bf16x8  __attribute__((ext_vector_type(8)));
typedef short bf16x16 __attribute__((ext_vector_type(16)));
typedef float f32x4   __attribute__((ext_vector_type(4)));

#define GLOAD_LDS16(g, l) __builtin_amdgcn_global_load_lds( \
    (const __attribute__((address_space(1))) void*)(g), \
    (__attribute__((address_space(3))) void*)(l), 16, 0, 0)

__device__ __forceinline__ unsigned short f2bf(float f) {
    unsigned int u = __float_as_uint(f);
    u += 0x7FFFu + ((u >> 16) & 1u);           // RNE
    return (unsigned short)(u >> 16);
}
__device__ __forceinline__ float cinv(int p) { return (p < 16) ? (1.0f/43.0f) : (1.0f/42.0f); }

// ---------------- kernel A: x (fp32) -> xb (bf16), pure stream ----------------
__global__ void x2bf(const float* __restrict__ x, unsigned short* __restrict__ xb) {
    size_t idx = (size_t)blockIdx.x * blockDim.x + threadIdx.x;   // one 8-elem chunk
    const f32x4* src = (const f32x4*)(x + idx * 8);
    f32x4 lo = src[0], hi = src[1];
    union { unsigned int u[4]; bf16x8 v; } r;
    asm("v_cvt_pk_bf16_f32 %0, %1, %2" : "=v"(r.u[0]) : "v"(lo[0]), "v"(lo[1]));
    asm("v_cvt_pk_bf16_f32 %0, %1, %2" : "=v"(r.u[1]) : "v"(lo[2]), "v"(lo[3]));
    asm("v_cvt_pk_bf16_f32 %0, %1, %2" : "=v"(r.u[2]) : "v"(hi[0]), "v"(hi[1]));
    asm("v_cvt_pk_bf16_f32 %0, %1, %2" : "=v"(r.u[3]) : "v"(hi[2]), "v"(hi[3]));
    *(bf16x8*)(xb + idx * 8) = r.v;
}

// ---------------- kernel B: fused = bias broadcast + per-phase column sums ----------------
__global__ void init_phase(const float* __restrict__ be0, const float* __restrict__ be1,
                           const float* __restrict__ be2, const float* __restrict__ We1,
                           const float* __restrict__ We2, float* __restrict__ fused,
                           float* __restrict__ u) {
    int idx = blockIdx.x * blockDim.x + threadIdx.x;
    if (idx < BATCH * NH3) {
        int j = idx % NH3;
        float b = (j < HDIM) ? be0[j] : (j < 2*HDIM ? be1[j - HDIM] : be2[j - 2*HDIM]);
        fused[idx] = b;
    }
    if (idx < 2 * PERIOD * FH) {
        int w   = idx / (PERIOD * FH);
        int rem = idx % (PERIOD * FH);
        int p   = rem / FH;
        int fh  = rem % FH;
        const float* W = (w == 0) ? We1 : We2;
        float s = 0.f;
        for (int l = p; l < L_LEN; l += PERIOD) s += W[(size_t)l * FH + fh];
        u[idx] = s;
    }
}

// ---------------- kernel C: build W' (bf16), layout Wp[n][k], k = l*16 + f ----------------
__global__ void build_wp(const float* __restrict__ We0, const float* __restrict__ We2,
                         const float* __restrict__ u, unsigned short* __restrict__ Wp) {
    __shared__ unsigned short tile[3][16][NLB][16];   // [mat][h][l][f] = 24 KB
    int f  = threadIdx.x >> 4;
    int hl = threadIdx.x & 15;
    int h  = blockIdx.x * 16 + hl;
    int l0 = blockIdx.y * NLB;
    int fh = f * HDIM + h;
    const float* u1 = u;
    const float* u2 = u + PERIOD * FH;

    float Sv1 = 0.f, Sv2 = 0.f;
    for (int p = 0; p < PERIOD; ++p) {
        float ci = cinv(p);
        Sv1 += u1[p * FH + fh] * ci;
        Sv2 += u2[p * FH + fh] * ci;
    }
    float s0 = 0.f, s2 = 0.f;
    for (int j = l0 - THALF; j <= l0 + THALF; ++j)
        if (j >= 0 && j < L_LEN) { s0 += We0[(size_t)j * FH + fh]; s2 += We2[(size_t)j * FH + fh]; }

    const float inv25 = 1.0f / 25.0f;
    for (int l = l0; l < l0 + NLB; ++l) {
        float out0 = s0 * inv25;
        float mav1, mav2;
        if (l >= THALF && l < L_LEN - THALF) {
            int pr = (l + THALF) % PERIOD;
            float cr = cinv(pr);
            mav1 = (Sv1 + u1[pr * FH + fh] * cr) * inv25;
            mav2 = (Sv2 + u2[pr * FH + fh] * cr) * inv25;
        } else {
            mav1 = 0.f; mav2 = 0.f;
            for (int dl = -THALF; dl <= THALF; ++dl) {
                int j = l + dl;
                if (j >= 0 && j < L_LEN) {
                    int p = j % PERIOD;
                    float ci = cinv(p);
                    mav1 += u1[p * FH + fh] * ci;
                    mav2 += u2[p * FH + fh] * ci;
                }
            }
            mav1 *= inv25; mav2 *= inv25;
        }
        int   pl  = l % PERIOD;
        float cl  = cinv(pl);
        float v1l = u1[pl * FH + fh] * cl;
        float v2l = u2[pl * FH + fh] * cl;
        float out1 = v1l - mav1;
        float out2 = We2[(size_t)l * FH + fh] - s2 * inv25 - v2l + mav2;

        tile[0][hl][l - l0][f] = f2bf(out0);
        tile[1][hl][l - l0][f] = f2bf(out1);
        tile[2][hl][l - l0][f] = f2bf(out2);

        int jr = l - THALF, ja = l + THALF + 1;
        if (jr >= 0)    { s0 -= We0[(size_t)jr * FH + fh]; s2 -= We2[(size_t)jr * FH + fh]; }
        if (ja < L_LEN) { s0 += We0[(size_t)ja * FH + fh]; s2 += We2[(size_t)ja * FH + fh]; }
    }
    __syncthreads();

    int h2 = threadIdx.x >> 4, ll = threadIdx.x & 15;
    int hrow = blockIdx.x * 16 + h2;
    #pragma unroll
    for (int m = 0; m < 3; ++m) {
        bf16x16 v = *(const bf16x16*)&tile[m][h2][ll][0];
        *(bf16x16*)&Wp[(size_t)(m * HDIM + hrow) * DDIM + (size_t)(l0 + ll) * FDIM] = v;
    }
}

// ---------------- kernel D: gemm, m97-style global_load_lds double-buffer ----------------
#define GBM 128
#define GBN 128
#define GBK 64
#define GSPLITK 16
#define GKSPLIT (DDIM / GSPLITK)     // 1024
#define GKSTEPS (GKSPLIT / GBK)      // 16

__launch_bounds__(256, 2)
__global__ void gemm_lds(const unsigned short* __restrict__ xb,
                         const unsigned short* __restrict__ Wp,
                         float* __restrict__ fused) {
    __shared__ unsigned short As[2][GBM * GBK];   // 16 KB each buf
    __shared__ unsigned short Bs[2][GBN * GBK];
    int tid = threadIdx.x, wave = tid >> 6, lane = tid & 63;
    int wm = wave >> 1, wn = wave & 1;
    int m0 = blockIdx.x * GBM, n0 = blockIdx.y * GBN, k0 = blockIdx.z * GKSPLIT;

    int srow = lane >> 3;                  // row within 8-row staging group
    int scol = (lane & 7) * 8;             // bf16 col offset within row
    const unsigned short* ga0 = xb + (size_t)m0 * DDIM + k0;
    const unsigned short* gb0 = Wp + (size_t)n0 * DDIM + k0;

    f32x4 acc[4][4] = {};

    auto stage = [&](int buf, int s) {
        #pragma unroll
        for (int q = 0; q < 4; ++q) {
            int r0  = (wave * 4 + q) * 8;              // first of 8 rows = 1KB chunk
            int row = r0 + srow;
            const unsigned short* ga = ga0 + (size_t)row * DDIM + s * GBK + scol;
            const unsigned short* gb = gb0 + (size_t)row * DDIM + s * GBK + scol;
            GLOAD_LDS16(ga, &As[buf][r0 * GBK]);       // HW: base + lane*16B
            GLOAD_LDS16(gb, &Bs[buf][r0 * GBK]);
        }
    };

    stage(0, 0);
    __syncthreads();

    int frow = lane & 15, kof = (lane >> 4) * 8;   // kof elems: 0,8,16,24
    for (int s = 0; s < GKSTEPS; ++s) {
        int buf = s & 1;
        if (s + 1 < GKSTEPS) stage(buf ^ 1, s + 1);    // async prefetch next tile
        #pragma unroll
        for (int ks = 0; ks < 2; ++ks) {
            bf16x8 av[4], bv[4];
            #pragma unroll
            for (int i = 0; i < 4; ++i) {
                av[i] = *(const bf16x8*)&As[buf][(wm*64 + i*16 + frow) * GBK + ks*32 + kof];
                bv[i] = *(const bf16x8*)&Bs[buf][(wn*64 + i*16 + frow) * GBK + ks*32 + kof];
            }
            #pragma unroll
            for (int i = 0; i < 4; ++i)
                #pragma unroll
                for (int j = 0; j < 4; ++j)
                    acc[i][j] = __builtin_amdgcn_mfma_f32_16x16x32_bf16(av[i], bv[j], acc[i][j], 0, 0, 0);
        }
        __syncthreads();   // drains vmcnt (staged loads) + lgkm; swap bufs
    }

    int orow = (lane >> 4) * 4, ocol = lane & 15;   // C/D: col=lane&15, row=(lane>>4)*4+r
    #pragma unroll
    for (int i = 0; i < 4; ++i)
        #pragma unroll
        for (int j = 0; j < 4; ++j)
            #pragma unroll
            for (int r = 0; r < 4; ++r)
                atomicAdd(&fused[(size_t)(m0 + wm*64 + i*16 + orow + r) * NH3
                                 + (n0 + wn*64 + j*16 + ocol)], acc[i][j][r]);
}

// ---------------- fallback gemm (round-2, fp32 A path) ----------------
#define BM 128
#define BN 128
#define BK 32
#define SPLITK 16
#define KSPLIT (DDIM / SPLITK)
#define KSTEPS (KSPLIT / BK)
#define LDP 40

__launch_bounds__(256, 2)
__global__ void gemm_main(const float* __restrict__ x, const unsigned short* __restrict__ Wp,
                          float* __restrict__ fused) {
    __shared__ unsigned short As[BM * LDP];
    __shared__ unsigned short Bs[BN * LDP];
    int tid  = threadIdx.x;
    int m0   = blockIdx.x * BM;
    int n0   = blockIdx.y * BN;
    int k0   = blockIdx.z * KSPLIT;
    int wave = tid >> 6, lane = tid & 63;
    int wm = wave >> 1, wn = wave & 1;
    int ar = tid >> 1;
    int ah = (tid & 1) * 16;
    const float*          xg = x  + (size_t)(m0 + ar) * DDIM + k0 + ah;
    const unsigned short* bg = Wp + (size_t)(n0 + ar) * DDIM + k0 + ah;

    f32x4  acc[4][4] = {};
    f32x4  areg[4];
    bf16x8 breg[2];

    auto load_tile = [&](int step) {
        const float* xa = xg + step * BK;
        #pragma unroll
        for (int i = 0; i < 4; ++i) areg[i] = *(const f32x4*)(xa + i * 4);
        const unsigned short* bb = bg + step * BK;
        breg[0] = *(const bf16x8*)(bb);
        breg[1] = *(const bf16x8*)(bb + 8);
    };
    auto store_tile = [&]() {
        #pragma unroll
        for (int v = 0; v < 2; ++v) {
            bf16x8 ab;
            #pragma unroll
            for (int j = 0; j < 8; ++j) {
                int e = v * 8 + j;
                ab[j] = (short)f2bf(areg[e >> 2][e & 3]);
            }
            *(bf16x8*)&As[ar * LDP + ah + v * 8] = ab;
            *(bf16x8*)&Bs[ar * LDP + ah + v * 8] = breg[v];
        }
    };

    int frow = lane & 15;
    int kof  = (lane >> 4) * 8;
    load_tile(0); store_tile(); __syncthreads();
    for (int step = 0; step < KSTEPS; ++step) {
        if (step + 1 < KSTEPS) load_tile(step + 1);
        bf16x8 af[4], bfr[4];
        #pragma unroll
        for (int i = 0; i < 4; ++i) {
            af[i]  = *(const bf16x8*)&As[(wm*64 + i*16 + frow) * LDP + kof];
            bfr[i] = *(const bf16x8*)&Bs[(wn*64 + i*16 + frow) * LDP + kof];
        }
        #pragma unroll
        for (int i = 0; i < 4; ++i)
            #pragma unroll
            for (int j = 0; j < 4; ++j)
                acc[i][j] = __builtin_amdgcn_mfma_f32_16x16x32_bf16(af[i], bfr[j], acc[i][j], 0, 0, 0);
        __syncthreads();
        if (step + 1 < KSTEPS) { store_tile(); __syncthreads(); }
    }
    int orow = (lane >> 4) * 4, ocol = lane & 15;
    #pragma unroll
    for (int i = 0; i < 4; ++i)
        #pragma unroll
        for (int j = 0; j < 4; ++j)
            #pragma unroll
            for (int r = 0; r < 4; ++r)
                atomicAdd(&fused[(size_t)(m0 + wm*64 + i*16 + orow + r) * NH3
                                 + (n0 + wn*64 + j*16 + ocol)], acc[i][j][r]);
}

// ---------------- kernel E: h = relu(fused @ Wf1 + bf1), 4 rows/block ----------------
__global__ void mlp1(const float* __restrict__ fused, const float* __restrict__ Wf1,
                     const float* __restrict__ bf1, float* __restrict__ h) {
    int b = blockIdx.x * 4 + (threadIdx.x >> 7);
    int j = threadIdx.x & 127;
    float acc = bf1[j];
    const float* fr = fused + (size_t)b * NH3;
    #pragma unroll 4
    for (int i = 0; i < NH3; ++i) acc = fmaf(fr[i], Wf1[(size_t)i * HDIM + j], acc);
    h[(size_t)b * HDIM + j] = fmaxf(acc, 0.f);
}

// ---------------- kernel F: out = h @ Wf2 + bf2 ----------------
__global__ void mlp2(const float* __restrict__ h, const float* __restrict__ Wf2,
                     const float* __restrict__ bf2, float* __restrict__ out) {
    int idx = blockIdx.x * blockDim.x + threadIdx.x;
    if (idx >= BATCH * NCLS) return;
    int b = idx / NCLS, c = idx % NCLS;
    float acc = bf2[c];
    const float* hr = h + (size_t)b * HDIM;
    for (int i = 0; i < HDIM; ++i) acc = fmaf(hr[i], Wf2[(size_t)i * NCLS + c], acc);
    out[idx] = acc;
}

extern "C" void kernel_launch(void* const* d_in, const int* in_sizes, int n_in,
                              void* d_out, int out_size, void* d_ws, size_t ws_size,
                              hipStream_t stream) {
    const float* x   = (const float*)d_in[0];
    const float* We0 = (const float*)d_in[1];
    const float* be0 = (const float*)d_in[2];
    const float* We1 = (const float*)d_in[3];
    const float* be1 = (const float*)d_in[4];
    const float* We2 = (const float*)d_in[5];
    const float* be2 = (const float*)d_in[6];
    const float* Wf1 = (const float*)d_in[7];
    const float* bf1 = (const float*)d_in[8];
    const float* Wf2 = (const float*)d_in[9];
    const float* bf2 = (const float*)d_in[10];
    float* out = (float*)d_out;

    char* wsb = (char*)d_ws;
    size_t off = 0;
    unsigned short* Wp = (unsigned short*)(wsb + off); off += (size_t)NH3 * DDIM * sizeof(unsigned short); // 12.6 MB
    float* u     = (float*)(wsb + off); off += (size_t)2 * PERIOD * FH * sizeof(float);                    // 0.39 MB
    float* fused = (float*)(wsb + off); off += (size_t)BATCH * NH3 * sizeof(float);                        // 1.57 MB
    float* hbuf  = (float*)(wsb + off); off += (size_t)BATCH * HDIM * sizeof(float);                       // 0.52 MB
    unsigned short* xbuf = (unsigned short*)(wsb + off);
    size_t need = off + (size_t)BATCH * DDIM * sizeof(unsigned short);                                     // +33.6 MB

    bool big_ws = (ws_size >= need);

    if (big_ws)
        x2bf<<<(BATCH * DDIM / 8) / 256, 256, 0, stream>>>(x, xbuf);
    init_phase<<<(BATCH * NH3 + 255) / 256, 256, 0, stream>>>(be0, be1, be2, We1, We2, fused, u);
    build_wp<<<dim3(8, 64), 256, 0, stream>>>(We0, We2, u, Wp);
    if (big_ws)
        gemm_lds<<<dim3(BATCH / GBM, NH3 / GBN, GSPLITK), 256, 0, stream>>>(xbuf, Wp, fused);
    else
        gemm_main<<<dim3(BATCH / BM, NH3 / BN, SPLITK), 256, 0, stream>>>(x, Wp, fused);
    mlp1<<<BATCH / 4, 512, 0, stream>>>(fused, Wf1, bf1, hbuf);
    mlp2<<<(BATCH * NCLS + 255) / 256, 256, 0, stream>>>(hbuf, Wf2, bf2, out);
}

// Round 4
// 140.197 us; speedup vs baseline: 1.2591x; 1.2591x over previous
//
#include <hip/hip_runtime.h>

#define L_LEN  1024
#define FDIM   16
#define PERIOD 24
#define HDIM   128
#define BATCH  1024
#define DDIM   (L_LEN*FDIM)      // 16384
#define NH3    (3*HDIM)          // 384
#define THALF  12
#define NCLS   10
#define FH     (FDIM*HDIM)       // 2048
#define NLB    8                 // l-strip per build_wp block

typedef short bf16x8  __attribute__((ext_vector_type(8)));
typedef short bf16x16 __attribute__((ext_vector_type(16)));
typedef float f32x4   __attribute__((ext_vector_type(4)));

__device__ __forceinline__ unsigned short f2bf(float f) {
    unsigned int u = __float_as_uint(f);
    u += 0x7FFFu + ((u >> 16) & 1u);           // RNE
    return (unsigned short)(u >> 16);
}
__device__ __forceinline__ float cinv(int p) { return (p < 16) ? (1.0f/43.0f) : (1.0f/42.0f); }

// ---------------- kernel B: fused = bias broadcast + per-phase column sums ----------------
__global__ void init_phase(const float* __restrict__ be0, const float* __restrict__ be1,
                           const float* __restrict__ be2, const float* __restrict__ We1,
                           const float* __restrict__ We2, float* __restrict__ fused,
                           float* __restrict__ u) {
    int idx = blockIdx.x * blockDim.x + threadIdx.x;
    if (idx < BATCH * NH3) {
        int j = idx % NH3;
        float b = (j < HDIM) ? be0[j] : (j < 2*HDIM ? be1[j - HDIM] : be2[j - 2*HDIM]);
        fused[idx] = b;
    }
    if (idx < 2 * PERIOD * FH) {
        int w   = idx / (PERIOD * FH);
        int rem = idx % (PERIOD * FH);
        int p   = rem / FH;
        int fh  = rem % FH;
        const float* W = (w == 0) ? We1 : We2;
        float s = 0.f;
        for (int l = p; l < L_LEN; l += PERIOD) s += W[(size_t)l * FH + fh];
        u[idx] = s;
    }
}

// ---------------- kernel C: build W' (bf16) — register-window version ----------------
// grid (8 h-groups of 16, 128 l-strips of 8); block 256 = (f = tid>>4) x (h = tid&15).
// All window values preloaded to regs (independent loads, one latency); slide is reg-only.
__global__ void build_wp(const float* __restrict__ We0, const float* __restrict__ We2,
                         const float* __restrict__ u, unsigned short* __restrict__ Wp) {
    __shared__ unsigned short tile[3][16][NLB][16];   // [mat][h][l][f] = 12 KB
    int f  = threadIdx.x >> 4;
    int hl = threadIdx.x & 15;
    int h  = blockIdx.x * 16 + hl;
    int l0 = blockIdx.y * NLB;
    int fh = f * HDIM + h;
    const float* u1 = u;
    const float* u2 = u + PERIOD * FH;

    // window registers: j = l0-12 .. l0+NLB+12-1  (NLB+25 = 33 values each)
    float w0[NLB + 25], w2[NLB + 25];
    #pragma unroll
    for (int i = 0; i < NLB + 25; ++i) {
        int j = l0 - THALF + i;                      // uniform across block
        if (j >= 0 && j < L_LEN) {
            w0[i] = We0[(size_t)j * FH + fh];
            w2[i] = We2[(size_t)j * FH + fh];
        } else { w0[i] = 0.f; w2[i] = 0.f; }
    }

    float Sv1 = 0.f, Sv2 = 0.f;
    #pragma unroll
    for (int p = 0; p < PERIOD; ++p) {               // 48 independent loads
        float ci = cinv(p);
        Sv1 += u1[p * FH + fh] * ci;
        Sv2 += u2[p * FH + fh] * ci;
    }

    float s0 = 0.f, s2 = 0.f;
    #pragma unroll
    for (int i = 0; i < 25; ++i) { s0 += w0[i]; s2 += w2[i]; }

    const float inv25 = 1.0f / 25.0f;
    #pragma unroll
    for (int r = 0; r < NLB; ++r) {
        int l = l0 + r;
        float out0 = s0 * inv25;                     // (T We0)[l]
        float mav1, mav2;
        if (l >= THALF && l < L_LEN - THALF) {       // interior: Sv + repeat phase (l+12)%24
            int pr = (l + THALF) % PERIOD;
            float cr = cinv(pr);
            mav1 = (Sv1 + u1[pr * FH + fh] * cr) * inv25;
            mav2 = (Sv2 + u2[pr * FH + fh] * cr) * inv25;
        } else {                                     // edge blocks only (by in {0,1,126,127})
            mav1 = 0.f; mav2 = 0.f;
            #pragma unroll
            for (int dl = -THALF; dl <= THALF; ++dl) {
                int j = l + dl;
                if (j >= 0 && j < L_LEN) {
                    int p = j % PERIOD;
                    float ci = cinv(p);
                    mav1 += u1[p * FH + fh] * ci;
                    mav2 += u2[p * FH + fh] * ci;
                }
            }
            mav1 *= inv25; mav2 *= inv25;
        }
        int   pl  = l % PERIOD;
        float cl  = cinv(pl);
        float v1l = u1[pl * FH + fh] * cl;
        float v2l = u2[pl * FH + fh] * cl;
        float out1 = v1l - mav1;                                      // S^T We1
        float out2 = w2[r + THALF] - s2 * inv25 - v2l + mav2;         // (I-T-S)^T We2

        tile[0][hl][r][f] = f2bf(out0);
        tile[1][hl][r][f] = f2bf(out1);
        tile[2][hl][r][f] = f2bf(out2);

        s0 += w0[r + 25] - w0[r];                    // register-only slide
        s2 += w2[r + 25] - w2[r];
    }
    __syncthreads();

    // write phase: 384 chunks of 32B (all 16 f of one (m,h,l)), coalesced 256B runs
    for (int cid = threadIdx.x; cid < 3 * 16 * NLB; cid += 256) {
        int m  = cid / (16 * NLB);
        int rm = cid % (16 * NLB);
        int h2 = rm / NLB;
        int ll = rm % NLB;
        bf16x16 v = *(const bf16x16*)&tile[m][h2][ll][0];
        *(bf16x16*)&Wp[(size_t)(m * HDIM + blockIdx.x * 16 + h2) * DDIM
                       + (size_t)(l0 + ll) * FDIM] = v;
    }
}

// ---------------- kernel D: fused += x(fp32) @ Wp^T, reg-staged bf16 MFMA, split-K ----------------
#define GBM 64
#define GBN 128
#define GBK 64
#define GSPLIT 16
#define GKSPL (DDIM / GSPLIT)    // 1024
#define GKST  (GKSPL / GBK)      // 16
#define LDA   72                 // padded LDS stride: 144B = 36 dwords ≡ 4 mod 32 -> 2-way (free)
#define NWG   (16 * 3 * GSPLIT)  // 768 blocks, 768 % 8 == 0 (bijective XCD swizzle)

__launch_bounds__(256, 4)
__global__ void gemm2(const float* __restrict__ x, const unsigned short* __restrict__ Wp,
                      float* __restrict__ fused) {
    __shared__ unsigned short As[GBM * LDA];   // 9.2 KB
    __shared__ unsigned short Bs[GBN * LDA];   // 18.4 KB
    // XCD-aware bijective swizzle (NWG % 8 == 0)
    int bid = blockIdx.x;
    int swz = (bid & 7) * (NWG / 8) + (bid >> 3);
    int bz  = swz / 48;            // k-split 0..15
    int rem = swz % 48;
    int by  = rem / 16;            // n 0..2
    int bx  = rem % 16;            // m 0..15
    int m0 = bx * GBM, n0 = by * GBN, k0 = bz * GKSPL;
    int tid = threadIdx.x, lane = tid & 63, wave = tid >> 6;
    int wm = wave >> 1, wn = wave & 1;

    // staging maps
    int arow = tid >> 2, aseg = tid & 3;       // A: 64 rows x 64 fp32; 16 f32/thread
    int brow = tid >> 1, bhalf = tid & 1;      // B: 128 rows x 64 bf16; 32 bf16/thread
    const float*          ag = x  + (size_t)(m0 + arow) * DDIM + k0 + aseg * 16;
    const unsigned short* bg = Wp + (size_t)(n0 + brow) * DDIM + k0 + bhalf * 32;

    f32x4  acc[2][4] = {};
    f32x4  aR[4];
    bf16x8 bR[4];

    auto load = [&](int s) {
        const float* a = ag + s * GBK;
        #pragma unroll
        for (int i = 0; i < 4; ++i) aR[i] = *(const f32x4*)(a + 4 * i);
        const unsigned short* b = bg + s * GBK;
        #pragma unroll
        for (int i = 0; i < 4; ++i) bR[i] = *(const bf16x8*)(b + 8 * i);
    };
    auto store = [&]() {
        bf16x8 p0, p1;
        #pragma unroll
        for (int j = 0; j < 8; ++j) {
            p0[j] = (short)f2bf(aR[j >> 2][j & 3]);
            p1[j] = (short)f2bf(aR[2 + (j >> 2)][j & 3]);
        }
        *(bf16x8*)&As[arow * LDA + aseg * 16]     = p0;
        *(bf16x8*)&As[arow * LDA + aseg * 16 + 8] = p1;
        #pragma unroll
        for (int i = 0; i < 4; ++i)
            *(bf16x8*)&Bs[brow * LDA + bhalf * 32 + 8 * i] = bR[i];
    };

    load(0); store(); __syncthreads();

    int frow = lane & 15, kof = (lane >> 4) * 8;
    for (int s = 0; s < GKST; ++s) {
        if (s + 1 < GKST) load(s + 1);             // prefetch next tile into regs
        #pragma unroll
        for (int ks = 0; ks < 2; ++ks) {
            bf16x8 av[2], bv[4];
            #pragma unroll
            for (int i = 0; i < 2; ++i)
                av[i] = *(const bf16x8*)&As[(wm*32 + i*16 + frow) * LDA + ks*32 + kof];
            #pragma unroll
            for (int j = 0; j < 4; ++j)
                bv[j] = *(const bf16x8*)&Bs[(wn*64 + j*16 + frow) * LDA + ks*32 + kof];
            #pragma unroll
            for (int i = 0; i < 2; ++i)
                #pragma unroll
                for (int j = 0; j < 4; ++j)
                    acc[i][j] = __builtin_amdgcn_mfma_f32_16x16x32_bf16(av[i], bv[j], acc[i][j], 0, 0, 0);
        }
        __syncthreads();
        if (s + 1 < GKST) { store(); __syncthreads(); }
    }

    // epilogue: C/D layout col = lane&15, row = (lane>>4)*4 + reg  [m89/m91]
    int orow = (lane >> 4) * 4, ocol = lane & 15;
    #pragma unroll
    for (int i = 0; i < 2; ++i)
        #pragma unroll
        for (int j = 0; j < 4; ++j)
            #pragma unroll
            for (int r = 0; r < 4; ++r)
                atomicAdd(&fused[(size_t)(m0 + wm*32 + i*16 + orow + r) * NH3
                                 + (n0 + wn*64 + j*16 + ocol)], acc[i][j][r]);
}

// ---------------- kernel E: h = relu(fused @ Wf1 + bf1), 4 rows/block ----------------
__global__ void mlp1(const float* __restrict__ fused, const float* __restrict__ Wf1,
                     const float* __restrict__ bf1, float* __restrict__ h) {
    int b = blockIdx.x * 4 + (threadIdx.x >> 7);
    int j = threadIdx.x & 127;
    float acc = bf1[j];
    const float* fr = fused + (size_t)b * NH3;
    #pragma unroll 4
    for (int i = 0; i < NH3; ++i) acc = fmaf(fr[i], Wf1[(size_t)i * HDIM + j], acc);
    h[(size_t)b * HDIM + j] = fmaxf(acc, 0.f);
}

// ---------------- kernel F: out = h @ Wf2 + bf2 ----------------
__global__ void mlp2(const float* __restrict__ h, const float* __restrict__ Wf2,
                     const float* __restrict__ bf2, float* __restrict__ out) {
    int idx = blockIdx.x * blockDim.x + threadIdx.x;
    if (idx >= BATCH * NCLS) return;
    int b = idx / NCLS, c = idx % NCLS;
    float acc = bf2[c];
    const float* hr = h + (size_t)b * HDIM;
    for (int i = 0; i < HDIM; ++i) acc = fmaf(hr[i], Wf2[(size_t)i * NCLS + c], acc);
    out[idx] = acc;
}

extern "C" void kernel_launch(void* const* d_in, const int* in_sizes, int n_in,
                              void* d_out, int out_size, void* d_ws, size_t ws_size,
                              hipStream_t stream) {
    const float* x   = (const float*)d_in[0];
    const float* We0 = (const float*)d_in[1];
    const float* be0 = (const float*)d_in[2];
    const float* We1 = (const float*)d_in[3];
    const float* be1 = (const float*)d_in[4];
    const float* We2 = (const float*)d_in[5];
    const float* be2 = (const float*)d_in[6];
    const float* Wf1 = (const float*)d_in[7];
    const float* bf1 = (const float*)d_in[8];
    const float* Wf2 = (const float*)d_in[9];
    const float* bf2 = (const float*)d_in[10];
    float* out = (float*)d_out;

    char* wsb = (char*)d_ws;
    size_t off = 0;
    unsigned short* Wp = (unsigned short*)(wsb + off); off += (size_t)NH3 * DDIM * sizeof(unsigned short); // 12.6 MB
    float* u     = (float*)(wsb + off); off += (size_t)2 * PERIOD * FH * sizeof(float);                    // 0.39 MB
    float* fused = (float*)(wsb + off); off += (size_t)BATCH * NH3 * sizeof(float);                        // 1.57 MB
    float* hbuf  = (float*)(wsb + off); off += (size_t)BATCH * HDIM * sizeof(float);                       // 0.52 MB

    init_phase<<<(BATCH * NH3 + 255) / 256, 256, 0, stream>>>(be0, be1, be2, We1, We2, fused, u);
    build_wp<<<dim3(8, L_LEN / NLB), 256, 0, stream>>>(We0, We2, u, Wp);
    gemm2<<<NWG, 256, 0, stream>>>(x, Wp, fused);
    mlp1<<<BATCH / 4, 512, 0, stream>>>(fused, Wf1, bf1, hbuf);
    mlp2<<<(BATCH * NCLS + 255) / 256, 256, 0, stream>>>(hbuf, Wf2, bf2, out);
}